// Round 1
// baseline (78156.934 us; speedup 1.0000x reference)
//
#include <hip/hip_runtime.h>
#include <math.h>

// LSTM_360: SEQ=512, BATCH=128, IN=256, HID=1024, fp32.
// Strategy (round 1, correctness-first):
//  - prep: transpose weights to K-major (coalesced loads), bsum = bxh+bhh, zero h/c
//  - per step: fused GEMM (M=128,N=4096,K=1280) + cell update; then out-proj + log_softmax
//  - ws usage ~24 MiB

#define TT  512
#define BB  128
#define NIN 256
#define NH  1024
#define G4  4096

// ---------------- prep kernels ----------------

// src is [R][C]; dst is [C][R]
__global__ void transpose_k(const float* __restrict__ src, float* __restrict__ dst,
                            int R, int C) {
  __shared__ float tile[32][33];
  int rb = blockIdx.y * 32, cb = blockIdx.x * 32;
  int c = cb + threadIdx.x;
#pragma unroll
  for (int i = 0; i < 32; i += 8) {
    int r = rb + threadIdx.y + i;
    tile[threadIdx.y + i][threadIdx.x] = src[(size_t)r * C + c];
  }
  __syncthreads();
  int dc = rb + threadIdx.x;
#pragma unroll
  for (int i = 0; i < 32; i += 8) {
    int dr = cb + threadIdx.y + i;
    dst[(size_t)dr * R + dc] = tile[threadIdx.x][threadIdx.y + i];
  }
}

__global__ void bias_sum_k(const float* __restrict__ a, const float* __restrict__ b,
                           float* __restrict__ o, int n) {
  int i = blockIdx.x * blockDim.x + threadIdx.x;
  if (i < n) o[i] = a[i] + b[i];
}

// ---------------- recurrent step ----------------
// grid (NH/16=64, BB/32=4), 256 threads.
// Block tile: 32 batches x 16 j-cols x 4 gates. Thread: 2 batches x 1 j x 4 gates.
__global__ __launch_bounds__(256) void step_kernel(
    const float* __restrict__ inp_t,   // [BB][NIN]  (inp + t*BB*NIN)
    const float* __restrict__ WxhT,    // [NIN][G4]
    const float* __restrict__ WhhT,    // [NH][G4]
    const float* __restrict__ bsum,    // [G4] = bxh + bhh
    const float* __restrict__ h_in,    // [BB][NH]
    float* __restrict__ h_out,         // [BB][NH]
    float* __restrict__ c)             // [BB][NH]
{
  __shared__ float A_s[32][36];        // [b_local][k], pad 36 (16B-aligned rows, conflict-free)
  __shared__ float W_s[32][64];        // [k][jl*4 + gate]

  const int tid = threadIdx.x;
  const int jl  = tid & 15;
  const int bg  = tid >> 4;            // 0..15
  const int b0  = blockIdx.y * 32;
  const int j0  = blockIdx.x * 16;
  const int j   = j0 + jl;

  const int bl  = tid >> 3;            // 0..31 (A loader row)
  const int kl4 = (tid & 7) * 4;       // A loader k offset

  float4 acc0 = make_float4(0.f, 0.f, 0.f, 0.f);
  float4 acc1 = make_float4(0.f, 0.f, 0.f, 0.f);

  for (int kc = 0; kc < NIN + NH; kc += 32) {
    // ---- stage A tile: 32 b x 32 k ----
    {
      const float* arow = (kc < NIN) ? (inp_t + (b0 + bl) * NIN + kc)
                                     : (h_in  + (b0 + bl) * NH + (kc - NIN));
      float4 a = *(const float4*)(arow + kl4);
      *(float4*)&A_s[bl][kl4] = a;
    }
    // ---- stage W tile: 32 k x (16 j x 4 gate) ----
    for (int u = tid; u < 512; u += 256) {
      int kl  = u >> 4;                // 0..31
      int rem = u & 15;
      int jg  = rem & 3;               // j-group of 4
      int g   = rem >> 2;              // gate 0..3 (i,f,g,o)
      const float* wrow = (kc < NIN) ? (WxhT + (size_t)(kc + kl) * G4)
                                     : (WhhT + (size_t)(kc - NIN + kl) * G4);
      float4 w = *(const float4*)(wrow + g * NH + j0 + jg * 4);
      W_s[kl][(jg * 4 + 0) * 4 + g] = w.x;
      W_s[kl][(jg * 4 + 1) * 4 + g] = w.y;
      W_s[kl][(jg * 4 + 2) * 4 + g] = w.z;
      W_s[kl][(jg * 4 + 3) * 4 + g] = w.w;
    }
    __syncthreads();
#pragma unroll
    for (int k = 0; k < 32; ++k) {
      float a0 = A_s[bg][k];
      float a1 = A_s[bg + 16][k];
      float4 w = *(const float4*)&W_s[k][jl * 4];
      acc0.x += a0 * w.x; acc0.y += a0 * w.y; acc0.z += a0 * w.z; acc0.w += a0 * w.w;
      acc1.x += a1 * w.x; acc1.y += a1 * w.y; acc1.z += a1 * w.z; acc1.w += a1 * w.w;
    }
    __syncthreads();
  }

  const float bi = bsum[j];
  const float bf = bsum[NH + j];
  const float bgc = bsum[2 * NH + j];
  const float bo = bsum[3 * NH + j];

#pragma unroll
  for (int m = 0; m < 2; ++m) {
    const int b = b0 + bg + m * 16;
    const float4 acc = m ? acc1 : acc0;
    const float gi = acc.x + bi;
    const float gf = acc.y + bf;
    const float gg = acc.z + bgc;
    const float go = acc.w + bo;
    const float si = 1.f / (1.f + expf(-gi));
    const float sf = 1.f / (1.f + expf(-gf));
    const float so = 1.f / (1.f + expf(-go));
    const float tg = tanhf(gg);
    const size_t idx = (size_t)b * NH + j;
    const float cn = sf * c[idx] + si * tg;
    c[idx] = cn;
    h_out[idx] = so * tanhf(cn);
  }
}

// ---------------- output projection + log_softmax ----------------
// grid BB/2 = 64 blocks, 256 threads. Block handles 2 batches; thread = 1 output col.
__global__ __launch_bounds__(256) void out_kernel(
    const float* __restrict__ h,       // [BB][NH] (this step's h)
    const float* __restrict__ WoutT,   // [NH][NIN]
    const float* __restrict__ bout,    // [NIN]
    float* __restrict__ out_t)         // [BB][NIN] (out + t*BB*NIN)
{
  __shared__ float h_s[2 * NH];
  __shared__ float red_s[8];
  const int tid = threadIdx.x;
  const int b0 = blockIdx.x * 2;

  for (int u = tid; u < 512; u += 256)
    *(float4*)&h_s[u * 4] = *(const float4*)(h + (size_t)b0 * NH + u * 4);
  __syncthreads();

  float acc0 = 0.f, acc1 = 0.f;
#pragma unroll 4
  for (int jj = 0; jj < NH; ++jj) {
    float w = WoutT[(size_t)jj * NIN + tid];
    acc0 += h_s[jj] * w;
    acc1 += h_s[NH + jj] * w;
  }
  float l0 = acc0 + bout[tid];
  float l1 = acc1 + bout[tid];

  // block-wide max (two rows)
  float m0 = l0, m1 = l1;
#pragma unroll
  for (int off = 32; off > 0; off >>= 1) {
    m0 = fmaxf(m0, __shfl_xor(m0, off));
    m1 = fmaxf(m1, __shfl_xor(m1, off));
  }
  if ((tid & 63) == 0) { red_s[tid >> 6] = m0; red_s[4 + (tid >> 6)] = m1; }
  __syncthreads();
  m0 = fmaxf(fmaxf(red_s[0], red_s[1]), fmaxf(red_s[2], red_s[3]));
  m1 = fmaxf(fmaxf(red_s[4], red_s[5]), fmaxf(red_s[6], red_s[7]));
  __syncthreads();

  float e0 = expf(l0 - m0), e1 = expf(l1 - m1);
  float s0 = e0, s1 = e1;
#pragma unroll
  for (int off = 32; off > 0; off >>= 1) {
    s0 += __shfl_xor(s0, off);
    s1 += __shfl_xor(s1, off);
  }
  if ((tid & 63) == 0) { red_s[tid >> 6] = s0; red_s[4 + (tid >> 6)] = s1; }
  __syncthreads();
  s0 = red_s[0] + red_s[1] + red_s[2] + red_s[3];
  s1 = red_s[4] + red_s[5] + red_s[6] + red_s[7];

  out_t[(size_t)(b0 + 0) * NIN + tid] = l0 - m0 - logf(s0);
  out_t[(size_t)(b0 + 1) * NIN + tid] = l1 - m1 - logf(s1);
}

// ---------------- launcher ----------------

extern "C" void kernel_launch(void* const* d_in, const int* in_sizes, int n_in,
                              void* d_out, int out_size, void* d_ws, size_t ws_size,
                              hipStream_t stream) {
  const float* inp  = (const float*)d_in[0];   // [TT][BB][NIN]
  const float* Wxh  = (const float*)d_in[1];   // [G4][NIN]
  const float* bxh  = (const float*)d_in[2];   // [G4]
  const float* Whh  = (const float*)d_in[3];   // [G4][NH]
  const float* bhh  = (const float*)d_in[4];   // [G4]
  const float* Wout = (const float*)d_in[5];   // [NIN][NH]
  const float* bout = (const float*)d_in[6];   // [NIN]
  float* out = (float*)d_out;

  // workspace layout (floats): total ~5.9M floats (~24 MiB)
  float* ws    = (float*)d_ws;
  float* WxhT  = ws;                       // NIN*G4
  float* WhhT  = WxhT + (size_t)NIN * G4;  // NH*G4
  float* WoutT = WhhT + (size_t)NH * G4;   // NH*NIN
  float* bsum  = WoutT + (size_t)NH * NIN; // G4
  float* h0    = bsum + G4;                // BB*NH
  float* c     = h0 + (size_t)BB * NH;     // BB*NH  (adjacent to h0 for one memset)
  float* h1    = c + (size_t)BB * NH;      // BB*NH

  dim3 tb(32, 8);
  transpose_k<<<dim3(NIN / 32, G4 / 32), tb, 0, stream>>>(Wxh, WxhT, G4, NIN);
  transpose_k<<<dim3(NH / 32, G4 / 32), tb, 0, stream>>>(Whh, WhhT, G4, NH);
  transpose_k<<<dim3(NH / 32, NIN / 32), tb, 0, stream>>>(Wout, WoutT, NIN, NH);
  bias_sum_k<<<G4 / 256, 256, 0, stream>>>(bxh, bhh, bsum, G4);
  hipMemsetAsync(h0, 0, (size_t)2 * BB * NH * sizeof(float), stream);  // h0 + c

  float* hbuf[2] = {h0, h1};
  for (int t = 0; t < TT; ++t) {
    const float* h_in = hbuf[t & 1];
    float* h_out = hbuf[(t + 1) & 1];
    step_kernel<<<dim3(NH / 16, BB / 32), 256, 0, stream>>>(
        inp + (size_t)t * BB * NIN, WxhT, WhhT, bsum, h_in, h_out, c);
    out_kernel<<<BB / 2, 256, 0, stream>>>(h_out, WoutT, bout,
                                           out + (size_t)t * BB * NIN);
  }
}

// Round 2
// 12589.903 us; speedup vs baseline: 6.2079x; 6.2079x over previous
//
#include <hip/hip_runtime.h>
#include <math.h>

// LSTM_360 R2: bf16 MFMA recurrence, fused 3-stage pipeline per step.
// Stage A (blocks 0..255):   GEMM h_t gates (M=128,N=4096,K=1280) + cell update -> h_t (bf16)
// Stage B (blocks 256..287): logits for step t-1 = h_{t-1} @ Wout^T + bout (MFMA)
// Stage C (blocks 288..319): log_softmax for step t-2 -> out
// Weight layout: Wc[n][k], n = j*4 + gate (gate-interleaved) so each GEMM block's
// 64-col slice holds complete (i,f,g,o) quads for 16 hidden units.

#define TT  512
#define BB  128
#define NIN 256
#define NH  1024
#define G4  4096
#define KK  1280

typedef __bf16 bf16_t;
typedef bf16_t bf16x8 __attribute__((ext_vector_type(8)));
typedef float  f32x4  __attribute__((ext_vector_type(4)));

// ---------------- prep kernels ----------------

// Wc[n][k]: n = j*4+g ; k<256 -> Wxh[g*1024+j][k], else Whh[g*1024+j][k-256]
__global__ void conv_w_kernel(const float* __restrict__ Wxh,
                              const float* __restrict__ Whh,
                              bf16_t* __restrict__ Wc) {
  const int n = blockIdx.y;
  const int k = blockIdx.x * 256 + threadIdx.x;
  const int g = n & 3, j = n >> 2;
  float v = (k < NIN) ? Wxh[(size_t)(g * NH + j) * NIN + k]
                      : Whh[(size_t)(g * NH + j) * NH + (k - NIN)];
  Wc[(size_t)n * KK + k] = (bf16_t)v;
}

// generic fp32 -> bf16 (4 elems/thread)
__global__ void conv_f2b_kernel(const float* __restrict__ src,
                                bf16_t* __restrict__ dst, int n4) {
  int i = blockIdx.x * 256 + threadIdx.x;
  if (i < n4) {
    float4 v = ((const float4*)src)[i];
    dst[i * 4 + 0] = (bf16_t)v.x;
    dst[i * 4 + 1] = (bf16_t)v.y;
    dst[i * 4 + 2] = (bf16_t)v.z;
    dst[i * 4 + 3] = (bf16_t)v.w;
  }
}

// bsum4[j*4+g] = bxh[g*1024+j] + bhh[g*1024+j]
__global__ void prep_bias_kernel(const float* __restrict__ bxh,
                                 const float* __restrict__ bhh,
                                 float* __restrict__ bsum4) {
  int n = blockIdx.x * 256 + threadIdx.x;  // 0..4095
  int g = n & 3, j = n >> 2;
  bsum4[n] = bxh[g * NH + j] + bhh[g * NH + j];
}

// ---------------- fused per-step kernel ----------------

__global__ __launch_bounds__(256) void fused_step(
    int t,
    const bf16_t* __restrict__ x_bf,    // [TT][BB][NIN]
    const bf16_t* __restrict__ Wc,      // [G4][KK]
    const float*  __restrict__ bsum4,   // [G4] gate-interleaved
    const bf16_t* __restrict__ h_cur,   // [BB][NH] = h_{t-1}
    bf16_t*       __restrict__ h_next,  // [BB][NH] = h_t
    float*        __restrict__ c,       // [BB][NH]
    const bf16_t* __restrict__ WoutB,   // [NIN][NH] row-major (B^T rows)
    const float*  __restrict__ bout,    // [NIN]
    float*        __restrict__ logits_w,// [BB][NIN] write (step t-1)
    const float*  __restrict__ logits_r,// [BB][NIN] read  (step t-2)
    float*        __restrict__ out)     // [TT][BB][NIN]
{
  const int blk  = blockIdx.x;
  const int tid  = threadIdx.x;
  const int lane = tid & 63;
  const int wv   = tid >> 6;
  const int l16  = lane & 15;
  const int lq   = lane >> 4;   // quad 0..3

  if (blk < 256) {
    // ---- Stage A: recurrent GEMM + cell update ----
    if (t >= TT) return;
    __shared__ float gs[32][68];   // gate preacts, pad 68 (16B-aligned rows)
    const int bm = (blk & 3) * 32;
    const int bn = (blk >> 2) * 64;
    const int wm = wv & 1, wn = wv >> 1;
    const int m0 = bm + wm * 16;
    const int n0 = bn + wn * 32;

    const bf16_t* ax  = x_bf + (size_t)t * BB * NIN + (size_t)(m0 + l16) * NIN + lq * 8;
    const bf16_t* ah  = h_cur + (size_t)(m0 + l16) * NH + lq * 8;
    const bf16_t* b0p = Wc + (size_t)(n0 + l16) * KK + lq * 8;
    const bf16_t* b1p = Wc + (size_t)(n0 + 16 + l16) * KK + lq * 8;

    f32x4 acc0 = {0.f, 0.f, 0.f, 0.f};
    f32x4 acc1 = {0.f, 0.f, 0.f, 0.f};

#pragma unroll 4
    for (int kk = 0; kk < NIN; kk += 32) {
      bf16x8 a  = *(const bf16x8*)(ax + kk);
      bf16x8 b0 = *(const bf16x8*)(b0p + kk);
      bf16x8 b1 = *(const bf16x8*)(b1p + kk);
      acc0 = __builtin_amdgcn_mfma_f32_16x16x32_bf16(a, b0, acc0, 0, 0, 0);
      acc1 = __builtin_amdgcn_mfma_f32_16x16x32_bf16(a, b1, acc1, 0, 0, 0);
    }
#pragma unroll 4
    for (int kk = 0; kk < NH; kk += 32) {
      bf16x8 a  = *(const bf16x8*)(ah + kk);
      bf16x8 b0 = *(const bf16x8*)(b0p + NIN + kk);
      bf16x8 b1 = *(const bf16x8*)(b1p + NIN + kk);
      acc0 = __builtin_amdgcn_mfma_f32_16x16x32_bf16(a, b0, acc0, 0, 0, 0);
      acc1 = __builtin_amdgcn_mfma_f32_16x16x32_bf16(a, b1, acc1, 0, 0, 0);
    }

    // D layout: col = lane&15, row = (lane>>4)*4 + reg
#pragma unroll
    for (int r = 0; r < 4; ++r) {
      gs[wm * 16 + lq * 4 + r][wn * 32 + l16]      = acc0[r];
      gs[wm * 16 + lq * 4 + r][wn * 32 + 16 + l16] = acc1[r];
    }
    __syncthreads();

#pragma unroll
    for (int p = 0; p < 2; ++p) {
      const int u  = tid + p * 256;
      const int bl = u >> 4, jl = u & 15;
      float4 g4 = *(const float4*)&gs[bl][jl * 4];
      const int jg = (bn >> 2) + jl;
      float4 bs = ((const float4*)bsum4)[jg];
      const float gi = g4.x + bs.x;
      const float gf = g4.y + bs.y;
      const float gg = g4.z + bs.z;
      const float go = g4.w + bs.w;
      const float si = 1.f / (1.f + __expf(-gi));
      const float sf = 1.f / (1.f + __expf(-gf));
      const float so = 1.f / (1.f + __expf(-go));
      const float tg = tanhf(gg);
      const size_t idx = (size_t)(bm + bl) * NH + jg;
      const float cn = sf * c[idx] + si * tg;
      c[idx] = cn;
      h_next[idx] = (bf16_t)(so * tanhf(cn));
    }
  } else if (blk < 288) {
    // ---- Stage B: logits for step t-1 ----
    if (t < 1 || t > TT) return;
    const int b2 = blk - 256;           // 0..31
    const int m0 = (b2 >> 2) * 16;      // 8 m-tiles
    const int n0 = (b2 & 3) * 64 + wv * 16;  // 4 n-blocks x 4 waves

    const bf16_t* ap = h_cur + (size_t)(m0 + l16) * NH + lq * 8;
    const bf16_t* bp = WoutB + (size_t)(n0 + l16) * NH + lq * 8;
    f32x4 acc = {0.f, 0.f, 0.f, 0.f};
#pragma unroll 4
    for (int kk = 0; kk < NH; kk += 32) {
      bf16x8 a = *(const bf16x8*)(ap + kk);
      bf16x8 b = *(const bf16x8*)(bp + kk);
      acc = __builtin_amdgcn_mfma_f32_16x16x32_bf16(a, b, acc, 0, 0, 0);
    }
    const int col = n0 + l16;
    const float bo = bout[col];
#pragma unroll
    for (int r = 0; r < 4; ++r)
      logits_w[(size_t)(m0 + lq * 4 + r) * NIN + col] = acc[r] + bo;
  } else {
    // ---- Stage C: log_softmax for step t-2 ----
    if (t < 2) return;
    __shared__ float red[2][4][4];
    const int b0 = (blk - 288) * 4;
    const float* lb = logits_r + (size_t)b0 * NIN;
    float v[4], mx[4], sm[4];
#pragma unroll
    for (int r = 0; r < 4; ++r) v[r] = lb[r * NIN + tid];
#pragma unroll
    for (int r = 0; r < 4; ++r) mx[r] = v[r];
#pragma unroll
    for (int off = 32; off > 0; off >>= 1)
#pragma unroll
      for (int r = 0; r < 4; ++r) mx[r] = fmaxf(mx[r], __shfl_xor(mx[r], off));
    if (lane == 0)
#pragma unroll
      for (int r = 0; r < 4; ++r) red[0][wv][r] = mx[r];
    __syncthreads();
#pragma unroll
    for (int r = 0; r < 4; ++r)
      mx[r] = fmaxf(fmaxf(red[0][0][r], red[0][1][r]),
                    fmaxf(red[0][2][r], red[0][3][r]));
#pragma unroll
    for (int r = 0; r < 4; ++r) sm[r] = __expf(v[r] - mx[r]);
#pragma unroll
    for (int off = 32; off > 0; off >>= 1)
#pragma unroll
      for (int r = 0; r < 4; ++r) sm[r] += __shfl_xor(sm[r], off);
    if (lane == 0)
#pragma unroll
      for (int r = 0; r < 4; ++r) red[1][wv][r] = sm[r];
    __syncthreads();
    float* ot = out + (size_t)(t - 2) * BB * NIN + (size_t)b0 * NIN;
#pragma unroll
    for (int r = 0; r < 4; ++r) {
      float S = red[1][0][r] + red[1][1][r] + red[1][2][r] + red[1][3][r];
      ot[r * NIN + tid] = v[r] - mx[r] - logf(S);
    }
  }
}

// ---------------- launcher ----------------

extern "C" void kernel_launch(void* const* d_in, const int* in_sizes, int n_in,
                              void* d_out, int out_size, void* d_ws, size_t ws_size,
                              hipStream_t stream) {
  const float* inp  = (const float*)d_in[0];
  const float* Wxh  = (const float*)d_in[1];
  const float* bxh  = (const float*)d_in[2];
  const float* Whh  = (const float*)d_in[3];
  const float* bhh  = (const float*)d_in[4];
  const float* Wout = (const float*)d_in[5];
  const float* bout = (const float*)d_in[6];
  float* out = (float*)d_out;

  // workspace carve (all 16B aligned); total ~46.1 MB
  char* p = (char*)d_ws;
  bf16_t* Wc    = (bf16_t*)p; p += (size_t)G4 * KK * 2;        // 10.49 MB
  bf16_t* x_bf  = (bf16_t*)p; p += (size_t)TT * BB * NIN * 2;  // 33.55 MB
  bf16_t* WoutB = (bf16_t*)p; p += (size_t)NIN * NH * 2;       // 0.52 MB
  bf16_t* h0    = (bf16_t*)p; p += (size_t)BB * NH * 2;        // 256 KB
  bf16_t* h1    = (bf16_t*)p; p += (size_t)BB * NH * 2;        // 256 KB
  float*  cbuf  = (float*)p;  p += (size_t)BB * NH * 4;        // 512 KB
  float*  bsum4 = (float*)p;  p += (size_t)G4 * 4;             // 16 KB
  float*  lg0   = (float*)p;  p += (size_t)BB * NIN * 4;       // 128 KB
  float*  lg1   = (float*)p;  p += (size_t)BB * NIN * 4;       // 128 KB

  conv_w_kernel<<<dim3(KK / 256, G4), 256, 0, stream>>>(Wxh, Whh, Wc);
  conv_f2b_kernel<<<(TT * BB * NIN / 4 + 255) / 256, 256, 0, stream>>>(
      inp, x_bf, TT * BB * NIN / 4);
  conv_f2b_kernel<<<(NIN * NH / 4 + 255) / 256, 256, 0, stream>>>(
      Wout, WoutB, NIN * NH / 4);
  prep_bias_kernel<<<G4 / 256, 256, 0, stream>>>(bxh, bhh, bsum4);
  hipMemsetAsync(h0, 0, (size_t)BB * NH * 2, stream);
  hipMemsetAsync(cbuf, 0, (size_t)BB * NH * 4, stream);

  bf16_t* hb[2] = {h0, h1};
  float*  lg[2] = {lg0, lg1};
  for (int t = 0; t < TT + 2; ++t) {
    fused_step<<<320, 256, 0, stream>>>(
        t, x_bf, Wc, bsum4,
        hb[t & 1], hb[(t + 1) & 1], cbuf,
        WoutB, bout,
        lg[t & 1],        // write: logits for step t-1
        lg[(t + 1) & 1],  // read:  logits for step t-2 (written at t-1)
        out);
  }
}